// Round 2
// baseline (5662.605 us; speedup 1.0000x reference)
//
#include <hip/hip_runtime.h>
#include <hip/hip_bf16.h>

typedef __hip_bfloat16 bf16;

__device__ __forceinline__ float u2f(unsigned short u) {
  return __uint_as_float(((unsigned)u) << 16);
}
__device__ __forceinline__ float b2f(bf16 v) { return __bfloat162float(v); }

// generic scalar load: isbf selects bf16 vs f32 interpretation of p
__device__ __forceinline__ float ldf(const void* p, long i, int isbf) {
  if (isbf) return b2f(((const bf16*)p)[i]);
  return ((const float*)p)[i];
}

__device__ __forceinline__ float4 loadx4(const bf16* X, long off) {
  const unsigned short* p = reinterpret_cast<const unsigned short*>(X) + off;
  ushort4 u = *reinterpret_cast<const ushort4*>(p);
  return make_float4(u2f(u.x), u2f(u.y), u2f(u.z), u2f(u.w));
}
__device__ __forceinline__ float4 loadx4(const float* X, long off) {
  return *reinterpret_cast<const float4*>(X + off);
}

// ---------------------------------------------------------------------------
// detect_dtype: decide if float inputs are bf16 (flag=1) or f32 (flag=0).
// Looks at low halfwords of the first nwords u32s of x: for bf16 data these
// are real bf16 values (exponent near 0x7F); for f32 data they are random
// mantissa bits (~9% false positive rate). Statistics over 4096 words.
// ---------------------------------------------------------------------------
__global__ __launch_bounds__(256) void detect_dtype(
    const unsigned* __restrict__ x, int nwords, int* __restrict__ flag) {
  __shared__ int cnt;
  if (threadIdx.x == 0) cnt = 0;
  __syncthreads();
  int c = 0;
  for (int i = threadIdx.x; i < nwords; i += 256) {
    unsigned h = x[i] & 0xFFFFu;
    unsigned e = (h >> 7) & 0xFFu;
    if ((e >= 0x70u && e <= 0x85u) || (h & 0x7FFFu) == 0u) c++;
  }
  atomicAdd(&cnt, c);
  __syncthreads();
  if (threadIdx.x == 0) *flag = (2 * cnt > nwords) ? 1 : 0;
}

// ---------------------------------------------------------------------------
// prep_weights: build transposed f32 combined weights in ws.
// Jobs {q0,q1,k0,k1,k2,v0,v1,v2,a0,a1}.
//   qkv jobs: WT[32][inD+4] (row c, input i; [c][inD]=bias, rest pad 0)
//   a jobs:   WT[32][36]
// k jobs fold arel[r] and prel[r]/sqrt(32); v jobs fold mrel[r].
// ---------------------------------------------------------------------------
__global__ __launch_bounds__(256) void prep_weights(
    const void* __restrict__ Wk, const void* __restrict__ bk,
    const void* __restrict__ Wq, const void* __restrict__ bq,
    const void* __restrict__ Wv, const void* __restrict__ bv,
    const void* __restrict__ Wa, const void* __restrict__ ba,
    const void* __restrict__ arel, const void* __restrict__ mrel,
    const void* __restrict__ prel, float* __restrict__ out, int inD,
    const int* __restrict__ flag) {
  const int isbf = *flag;
  const int per_qkv = 32 * (inD + 4);
  const int per_a = 32 * 36;
  const int total = 8 * per_qkv + 2 * per_a;
  int tid = blockIdx.x * 256 + threadIdx.x;
  if (tid >= total) return;
  int job, rem, S, IND;
  if (tid < 8 * per_qkv) {
    job = tid / per_qkv; rem = tid % per_qkv; S = inD + 4; IND = inD;
  } else {
    int t2 = tid - 8 * per_qkv;
    job = 8 + t2 / per_a; rem = t2 % per_a; S = 36; IND = 32;
  }
  int c = rem / S, i = rem % S;
  float val = 0.f;
  if (job < 2) {  // q: plain transpose of Wq[t], bias row
    int t = job;
    if (i < IND)       val = ldf(Wq, ((long)t * IND + i) * 32 + c, isbf);
    else if (i == IND) val = ldf(bq, t * 32 + c, isbf);
  } else if (job < 8) {  // k (2..4) / v (5..7): fold relation matrix
    bool isk = job < 5;
    int r = isk ? (job - 2) : (job - 5);
    int s = (r == 0) ? 0 : 1;  // EDGE_META src types {0,1,1}
    const void* W = isk ? Wk : Wv;
    const void* bb = isk ? bk : bv;
    const void* R = isk ? arel : mrel;
    const long Roff = (long)r * 1024;
    if (i <= IND) {
      float acc = 0.f;
      for (int j = 0; j < 32; j++) {
        float a = (i < IND) ? ldf(W, ((long)s * IND + i) * 32 + j, isbf)
                            : ldf(bb, s * 32 + j, isbf);
        acc += a * ldf(R, Roff + j * 32 + c, isbf);
      }
      if (isk) acc *= ldf(prel, r, isbf) * 0.17677669529663687f;  // prel/sqrt(32)
      val = acc;
    }
  } else {  // a: transpose of Wa[t], bias row
    int t = job - 8;
    if (i < 32)       val = ldf(Wa, ((long)t * 32 + i) * 32 + c, isbf);
    else if (i == 32) val = ldf(ba, t * 32 + c, isbf);
  }
  out[tid] = val;
}

// ---------------------------------------------------------------------------
// linear: Y[N][32] = X[N][IND] @ W + b,  WT f32 [32][IND+4] in LDS.
// Block 256 = 8 rowgroups x 32 cols; 4 rows/thread.
// ---------------------------------------------------------------------------
template <typename XT, int IND>
__device__ __forceinline__ void linear_body(const XT* __restrict__ X,
                                            const float* wc, float* __restrict__ Y,
                                            int row0, int col, int N) {
  float acc[4];
  const float bias = wc[IND];
#pragma unroll
  for (int r = 0; r < 4; r++) acc[r] = bias;
  if (row0 + 3 < N) {
#pragma unroll 4
    for (int j = 0; j < IND; j += 4) {
      float4 w4 = *reinterpret_cast<const float4*>(wc + j);
#pragma unroll
      for (int r = 0; r < 4; r++) {
        float4 xv = loadx4(X, (long)(row0 + r) * IND + j);
        acc[r] += xv.x * w4.x + xv.y * w4.y + xv.z * w4.z + xv.w * w4.w;
      }
    }
#pragma unroll
    for (int r = 0; r < 4; r++) Y[(long)(row0 + r) * 32 + col] = acc[r];
  } else if (row0 < N) {
    for (int j = 0; j < IND; j += 4) {
      float4 w4 = *reinterpret_cast<const float4*>(wc + j);
#pragma unroll
      for (int r = 0; r < 4; r++) {
        if (row0 + r < N) {
          float4 xv = loadx4(X, (long)(row0 + r) * IND + j);
          acc[r] += xv.x * w4.x + xv.y * w4.y + xv.z * w4.z + xv.w * w4.w;
        }
      }
    }
#pragma unroll
    for (int r = 0; r < 4; r++)
      if (row0 + r < N) Y[(long)(row0 + r) * 32 + col] = acc[r];
  }
}

template <int IND>
__global__ __launch_bounds__(256) void linear_ext(
    const void* __restrict__ X, const float* __restrict__ WTg,
    float* __restrict__ Y, int N, const int* __restrict__ flag) {
  constexpr int S = IND + 4;
  __shared__ float wt[32 * S];
  for (int idx = threadIdx.x; idx < 32 * S; idx += 256) wt[idx] = WTg[idx];
  __syncthreads();
  const int col = threadIdx.x & 31;
  const int row0 = blockIdx.x * 32 + (threadIdx.x >> 5) * 4;
  const float* wc = wt + col * S;
  if (*flag) linear_body<bf16, IND>((const bf16*)X, wc, Y, row0, col, N);
  else       linear_body<float, IND>((const float*)X, wc, Y, row0, col, N);
}

template <int IND>
__global__ __launch_bounds__(256) void linear_f32(
    const float* __restrict__ X, const float* __restrict__ WTg,
    float* __restrict__ Y, int N) {
  constexpr int S = IND + 4;
  __shared__ float wt[32 * S];
  for (int idx = threadIdx.x; idx < 32 * S; idx += 256) wt[idx] = WTg[idx];
  __syncthreads();
  const int col = threadIdx.x & 31;
  const int row0 = blockIdx.x * 32 + (threadIdx.x >> 5) * 4;
  linear_body<float, IND>(X, wt + col * S, Y, row0, col, N);
}

// ---------------------------------------------------------------------------
// Edge kernels: 8 lanes per edge for 32-wide rows.
// ---------------------------------------------------------------------------
__global__ __launch_bounds__(256) void score_kernel(
    const int* __restrict__ src, const int* __restrict__ dst, int E,
    const float* __restrict__ qT, const float* __restrict__ krel,
    float* __restrict__ scores, unsigned int* __restrict__ smax) {
  int t = blockIdx.x * 256 + threadIdx.x;
  int e = t >> 3, g = t & 7;
  if (e >= E) return;
  int s_ = src[e], d_ = dst[e];
  float4 qv = *reinterpret_cast<const float4*>(qT + (long)d_ * 32 + g * 4);
  float4 kv = *reinterpret_cast<const float4*>(krel + (long)s_ * 32 + g * 4);
  float acc = qv.x * kv.x + qv.y * kv.y + qv.z * kv.z + qv.w * kv.w;
  acc += __shfl_xor(acc, 1);
  acc += __shfl_xor(acc, 2);
  acc += __shfl_xor(acc, 4);
  if (g == 0) {
    scores[e] = acc;
    unsigned u = __float_as_uint(acc);
    u = (u & 0x80000000u) ? ~u : (u | 0x80000000u);  // order-preserving encode
    atomicMax(smax + d_, u);
  }
}

__global__ __launch_bounds__(256) void ex_kernel(
    const int* __restrict__ dst, int E, float* __restrict__ scores,
    const unsigned int* __restrict__ smax, float* __restrict__ den) {
  int e = blockIdx.x * 256 + threadIdx.x;
  if (e >= E) return;
  int d_ = dst[e];
  unsigned u = smax[d_];
  float m = __uint_as_float((u & 0x80000000u) ? (u ^ 0x80000000u) : ~u);
  float ex = __expf(scores[e] - m);
  scores[e] = ex;
  unsafeAtomicAdd(den + d_, ex);
}

__global__ __launch_bounds__(256) void scatter_kernel(
    const int* __restrict__ src, const int* __restrict__ dst, int E,
    const float* __restrict__ scores, const float* __restrict__ den,
    const float* __restrict__ vrel, float* __restrict__ outs) {
  int t = blockIdx.x * 256 + threadIdx.x;
  int e = t >> 3, g = t & 7;
  if (e >= E) return;
  int s_ = src[e], d_ = dst[e];
  float alpha = scores[e] / den[d_];
  float4 vv = *reinterpret_cast<const float4*>(vrel + (long)s_ * 32 + g * 4);
  float* o = outs + (long)d_ * 32 + g * 4;
  unsafeAtomicAdd(o + 0, alpha * vv.x);
  unsafeAtomicAdd(o + 1, alpha * vv.y);
  unsafeAtomicAdd(o + 2, alpha * vv.z);
  unsafeAtomicAdd(o + 3, alpha * vv.w);
}

__global__ __launch_bounds__(256) void gelu_kernel(
    const float* __restrict__ in, float* __restrict__ out, int n) {
  int i = blockIdx.x * 256 + threadIdx.x;
  if (i >= n) return;
  float x = in[i];
  out[i] = 0.5f * x * (1.f + erff(x * 0.70710678118654752f));
}

__global__ __launch_bounds__(256) void blend_kernel(
    const float* __restrict__ o, const float* __restrict__ xin,
    const void* __restrict__ skipg, void* __restrict__ out, int nAf, int total,
    const int* __restrict__ flag) {
  int i = blockIdx.x * 256 + threadIdx.x;
  if (i >= total) return;
  const int isbf = *flag;
  float g = ldf(skipg, (i < nAf) ? 0 : 1, isbf);
  float a = 1.f / (1.f + __expf(-g));
  float v = a * o[i] + (1.f - a) * xin[i];
  if (isbf) ((bf16*)out)[i] = __float2bfloat16(v);
  else      ((float*)out)[i] = v;
}

// ---------------------------------------------------------------------------
// Host-side: one HGT layer. EXT: x is external input (runtime dtype); else f32.
// ---------------------------------------------------------------------------
template <int IND, bool EXT>
static void run_layer(const void* xa, const void* xp, const int* flag,
                      const float* w, const int* e0, int E0, const int* e1,
                      int E1, const int* e2, int E2, float* q, float* outs,
                      float* kv, float* scores, unsigned* smax, float* den,
                      float* eout, int NA, int NP, int NMAX,
                      hipStream_t stream) {
  const long NAf = (long)NA * 32;
  const long NPf = (long)NP * 32;
  const int per_qkv = 32 * (IND + 4);
  const int per_a = 32 * 36;
  const float* qW[2] = {w, w + per_qkv};
  const float* kW[3] = {w + 2 * per_qkv, w + 3 * per_qkv, w + 4 * per_qkv};
  const float* vW[3] = {w + 5 * per_qkv, w + 6 * per_qkv, w + 7 * per_qkv};
  const float* aW[2] = {w + 8 * per_qkv, w + 8 * per_qkv + per_a};

  auto LIN = [&](const void* X, const float* W, float* Y, int N) {
    if constexpr (EXT)
      linear_ext<IND><<<(N + 31) / 32, 256, 0, stream>>>(X, W, Y, N, flag);
    else
      linear_f32<IND><<<(N + 31) / 32, 256, 0, stream>>>((const float*)X, W, Y, N);
  };

  // q for both node types
  LIN(xa, qW[0], q, NA);
  LIN(xp, qW[1], q + NAf, NP);
  // zero attention accumulators
  hipMemsetAsync(outs, 0, (size_t)(NAf + NPf) * 4, stream);

  const void* xs_[3] = {xa, xp, xp};
  const int ns_[3] = {NA, NP, NP};
  const int* ed_[3] = {e0, e1, e2};
  const int E_[3] = {E0, E1, E2};
  float* qdst_[3] = {q + NAf, q, q + NAf};
  float* odst_[3] = {outs + NAf, outs, outs + NAf};

  for (int r = 0; r < 3; r++) {
    const int E = E_[r];
    const int* srcp = ed_[r];
    const int* dstp = ed_[r] + E;
    // smax (encoded, init 0 == -inf) and den (0.f) are contiguous
    hipMemsetAsync(smax, 0, (size_t)NMAX * 8, stream);
    // k_rel directly from x via folded weights
    LIN(xs_[r], kW[r], kv, ns_[r]);
    score_kernel<<<((long)E * 8 + 255) / 256, 256, 0, stream>>>(
        srcp, dstp, E, qdst_[r], kv, scores, smax);
    ex_kernel<<<(E + 255) / 256, 256, 0, stream>>>(dstp, E, scores, smax, den);
    // v_rel overwrites kv (k_rel no longer needed)
    LIN(xs_[r], vW[r], kv, ns_[r]);
    scatter_kernel<<<((long)E * 8 + 255) / 256, 256, 0, stream>>>(
        srcp, dstp, E, scores, den, kv, odst_[r]);
  }

  // epilogue: gelu(outs) -> q (q is free now), then @Wa + ba -> eout
  int tot = (int)(NAf + NPf);
  gelu_kernel<<<(tot + 255) / 256, 256, 0, stream>>>(outs, q, tot);
  linear_f32<32><<<(NA + 31) / 32, 256, 0, stream>>>(q, aW[0], eout, NA);
  linear_f32<32><<<(NP + 31) / 32, 256, 0, stream>>>(q + NAf, aW[1], eout + NAf, NP);
}

extern "C" void kernel_launch(void* const* d_in, const int* in_sizes, int n_in,
                              void* d_out, int out_size, void* d_ws,
                              size_t ws_size, hipStream_t stream) {
  const void* x_a = d_in[0];
  const void* x_p = d_in[1];
  const int* e_w = (const int*)d_in[2];
  const int* e_wb = (const int*)d_in[3];
  const int* e_c = (const int*)d_in[4];
  const int NA = in_sizes[0] / 128;
  const int NP = in_sizes[1] / 128;
  const int E0 = in_sizes[2] / 2, E1 = in_sizes[3] / 2, E2 = in_sizes[4] / 2;
  const int NMAX = (NP > NA) ? NP : NA;
  int MAXE = E0 > E1 ? E0 : E1; if (E2 > MAXE) MAXE = E2;

  // ---- workspace layout (f32 units) ----
  const size_t W1SZ = 8 * 32 * 132 + 2 * 32 * 36;  // 36096
  const size_t W2SZ = 10 * 32 * 36;                // 11520
  const size_t NT32 = (size_t)(NA + NP) * 32;      // 9.6M
  const size_t KVSZ = (size_t)NMAX * 32;           // 6.4M
  int* flag = (int*)d_ws;
  float* w1 = (float*)d_ws + 16;  // 64B offset keeps alignment
  float* w2 = w1 + W1SZ;
  float* q = w2 + W2SZ;
  float* outs = q + NT32;
  float* x2 = outs + NT32;
  float* kv = x2 + NT32;
  float* scores = kv + KVSZ;
  unsigned* smax = (unsigned*)(scores + MAXE);
  float* den = (float*)(smax + NMAX);
  (void)ws_size; (void)n_in;

  // ---- dtype sniff (bf16 vs f32) on x_author ----
  detect_dtype<<<1, 256, 0, stream>>>((const unsigned*)x_a, 4096, flag);

  // ---- combined weights ----
  {
    int tot1 = 8 * 32 * 132 + 2 * 32 * 36;
    prep_weights<<<(tot1 + 255) / 256, 256, 0, stream>>>(
        d_in[5], d_in[6],    // Wk1, bk1
        d_in[7], d_in[8],    // Wq1, bq1
        d_in[9], d_in[10],   // Wv1, bv1
        d_in[11], d_in[12],  // Wa1, ba1
        d_in[14], d_in[15],  // arel1, mrel1
        d_in[16],            // prel1
        w1, 128, flag);
    int tot2 = 10 * 32 * 36;
    prep_weights<<<(tot2 + 255) / 256, 256, 0, stream>>>(
        d_in[17], d_in[18],  // Wk2, bk2
        d_in[19], d_in[20],  // Wq2, bq2
        d_in[21], d_in[22],  // Wv2, bv2
        d_in[23], d_in[24],  // Wa2, ba2
        d_in[26], d_in[27],  // arel2, mrel2
        d_in[28],            // prel2
        w2, 32, flag);
  }

  // ---- layer 1: x [128] -> x2 (f32), no skip ----
  run_layer<128, true>(x_a, x_p, flag, w1, e_w, E0, e_wb, E1, e_c, E2, q, outs,
                       kv, scores, smax, den, x2, NA, NP, NMAX, stream);

  // ---- layer 2: f32 x2 [32] -> outs (f32), then gated skip -> d_out ----
  run_layer<32, false>(x2, x2 + (size_t)NA * 32, flag, w2, e_w, E0, e_wb, E1,
                       e_c, E2, q, outs, kv, scores, smax, den, outs, NA, NP,
                       NMAX, stream);
  blend_kernel<<<(out_size + 255) / 256, 256, 0, stream>>>(
      outs, x2, d_in[13 + 12], d_out, NA * 32, out_size, flag);
}

// Round 3
// 2312.973 us; speedup vs baseline: 2.4482x; 2.4482x over previous
//
#include <hip/hip_runtime.h>
#include <hip/hip_bf16.h>

typedef __hip_bfloat16 bf16;

__device__ __forceinline__ float u2f(unsigned short u) {
  return __uint_as_float(((unsigned)u) << 16);
}
__device__ __forceinline__ float b2f(bf16 v) { return __bfloat162float(v); }

// generic scalar load: isbf selects bf16 vs f32 interpretation of p
__device__ __forceinline__ float ldf(const void* p, long i, int isbf) {
  if (isbf) return b2f(((const bf16*)p)[i]);
  return ((const float*)p)[i];
}

__device__ __forceinline__ float4 loadx4(const bf16* X, long off) {
  const unsigned short* p = reinterpret_cast<const unsigned short*>(X) + off;
  ushort4 u = *reinterpret_cast<const ushort4*>(p);
  return make_float4(u2f(u.x), u2f(u.y), u2f(u.z), u2f(u.w));
}
__device__ __forceinline__ float4 loadx4(const float* X, long off) {
  return *reinterpret_cast<const float4*>(X + off);
}

// ---------------------------------------------------------------------------
// detect_dtype: decide if float inputs are bf16 (flag=1) or f32 (flag=0).
// ---------------------------------------------------------------------------
__global__ __launch_bounds__(256) void detect_dtype(
    const unsigned* __restrict__ x, int nwords, int* __restrict__ flag) {
  __shared__ int cnt;
  if (threadIdx.x == 0) cnt = 0;
  __syncthreads();
  int c = 0;
  for (int i = threadIdx.x; i < nwords; i += 256) {
    unsigned h = x[i] & 0xFFFFu;
    unsigned e = (h >> 7) & 0xFFu;
    if ((e >= 0x70u && e <= 0x85u) || (h & 0x7FFFu) == 0u) c++;
  }
  atomicAdd(&cnt, c);
  __syncthreads();
  if (threadIdx.x == 0) *flag = (2 * cnt > nwords) ? 1 : 0;
}

// ---------------------------------------------------------------------------
// prep_weights: build transposed f32 combined weights in ws.
// Jobs {q0,q1,k0,k1,k2,v0,v1,v2,a0,a1}.
//   qkv jobs: WT[32][inD+4] (row c, input i; [c][inD]=bias, rest pad 0)
//   a jobs:   WT[32][36]
// k jobs fold arel[r] and prel[r]/sqrt(32); v jobs fold mrel[r].
// ---------------------------------------------------------------------------
__global__ __launch_bounds__(256) void prep_weights(
    const void* __restrict__ Wk, const void* __restrict__ bk,
    const void* __restrict__ Wq, const void* __restrict__ bq,
    const void* __restrict__ Wv, const void* __restrict__ bv,
    const void* __restrict__ Wa, const void* __restrict__ ba,
    const void* __restrict__ arel, const void* __restrict__ mrel,
    const void* __restrict__ prel, float* __restrict__ out, int inD,
    const int* __restrict__ flag) {
  const int isbf = *flag;
  const int per_qkv = 32 * (inD + 4);
  const int per_a = 32 * 36;
  const int total = 8 * per_qkv + 2 * per_a;
  int tid = blockIdx.x * 256 + threadIdx.x;
  if (tid >= total) return;
  int job, rem, S, IND;
  if (tid < 8 * per_qkv) {
    job = tid / per_qkv; rem = tid % per_qkv; S = inD + 4; IND = inD;
  } else {
    int t2 = tid - 8 * per_qkv;
    job = 8 + t2 / per_a; rem = t2 % per_a; S = 36; IND = 32;
  }
  int c = rem / S, i = rem % S;
  float val = 0.f;
  if (job < 2) {  // q: plain transpose of Wq[t], bias row
    int t = job;
    if (i < IND)       val = ldf(Wq, ((long)t * IND + i) * 32 + c, isbf);
    else if (i == IND) val = ldf(bq, t * 32 + c, isbf);
  } else if (job < 8) {  // k (2..4) / v (5..7): fold relation matrix
    bool isk = job < 5;
    int r = isk ? (job - 2) : (job - 5);
    int s = (r == 0) ? 0 : 1;  // EDGE_META src types {0,1,1}
    const void* W = isk ? Wk : Wv;
    const void* bb = isk ? bk : bv;
    const void* R = isk ? arel : mrel;
    const long Roff = (long)r * 1024;
    if (i <= IND) {
      float acc = 0.f;
      for (int j = 0; j < 32; j++) {
        float a = (i < IND) ? ldf(W, ((long)s * IND + i) * 32 + j, isbf)
                            : ldf(bb, s * 32 + j, isbf);
        acc += a * ldf(R, Roff + j * 32 + c, isbf);
      }
      if (isk) acc *= ldf(prel, r, isbf) * 0.17677669529663687f;  // prel/sqrt(32)
      val = acc;
    }
  } else {  // a: transpose of Wa[t], bias row
    int t = job - 8;
    if (i < 32)       val = ldf(Wa, ((long)t * 32 + i) * 32 + c, isbf);
    else if (i == 32) val = ldf(ba, t * 32 + c, isbf);
  }
  out[tid] = val;
}

// ---------------------------------------------------------------------------
// linear: Y[row*ldY + offY + col] = X[row] @ W + b,  WT f32 [32][IND+4] in LDS.
// Block 256 = 8 rowgroups x 32 cols; 4 rows/thread.
// ---------------------------------------------------------------------------
template <typename XT, int IND>
__device__ __forceinline__ void linear_body(const XT* __restrict__ X,
                                            const float* wc, float* __restrict__ Y,
                                            int row0, int col, int N, int ldY) {
  float acc[4];
  const float bias = wc[IND];
#pragma unroll
  for (int r = 0; r < 4; r++) acc[r] = bias;
  if (row0 + 3 < N) {
#pragma unroll 4
    for (int j = 0; j < IND; j += 4) {
      float4 w4 = *reinterpret_cast<const float4*>(wc + j);
#pragma unroll
      for (int r = 0; r < 4; r++) {
        float4 xv = loadx4(X, (long)(row0 + r) * IND + j);
        acc[r] += xv.x * w4.x + xv.y * w4.y + xv.z * w4.z + xv.w * w4.w;
      }
    }
#pragma unroll
    for (int r = 0; r < 4; r++) Y[(long)(row0 + r) * ldY + col] = acc[r];
  } else if (row0 < N) {
    for (int j = 0; j < IND; j += 4) {
      float4 w4 = *reinterpret_cast<const float4*>(wc + j);
#pragma unroll
      for (int r = 0; r < 4; r++) {
        if (row0 + r < N) {
          float4 xv = loadx4(X, (long)(row0 + r) * IND + j);
          acc[r] += xv.x * w4.x + xv.y * w4.y + xv.z * w4.z + xv.w * w4.w;
        }
      }
    }
#pragma unroll
    for (int r = 0; r < 4; r++)
      if (row0 + r < N) Y[(long)(row0 + r) * ldY + col] = acc[r];
  }
}

template <int IND>
__global__ __launch_bounds__(256) void linear_ext(
    const void* __restrict__ X, const float* __restrict__ WTg,
    float* __restrict__ Y, int N, int ldY, int offY,
    const int* __restrict__ flag) {
  constexpr int S = IND + 4;
  __shared__ float wt[32 * S];
  for (int idx = threadIdx.x; idx < 32 * S; idx += 256) wt[idx] = WTg[idx];
  __syncthreads();
  const int col = threadIdx.x & 31;
  const int row0 = blockIdx.x * 32 + (threadIdx.x >> 5) * 4;
  const float* wc = wt + col * S;
  if (*flag) linear_body<bf16, IND>((const bf16*)X, wc, Y + offY, row0, col, N, ldY);
  else       linear_body<float, IND>((const float*)X, wc, Y + offY, row0, col, N, ldY);
}

template <int IND>
__global__ __launch_bounds__(256) void linear_f32(
    const float* __restrict__ X, const float* __restrict__ WTg,
    float* __restrict__ Y, int N, int ldY, int offY) {
  constexpr int S = IND + 4;
  __shared__ float wt[32 * S];
  for (int idx = threadIdx.x; idx < 32 * S; idx += 256) wt[idx] = WTg[idx];
  __syncthreads();
  const int col = threadIdx.x & 31;
  const int row0 = blockIdx.x * 32 + (threadIdx.x >> 5) * 4;
  linear_body<float, IND>(X, wt + col * S, Y + offY, row0, col, N, ldY);
}

// ---------------------------------------------------------------------------
// CSR build: hist -> 2-level exclusive scan -> fill (rowptr becomes ends).
// ---------------------------------------------------------------------------
__global__ __launch_bounds__(256) void hist_kernel(const int* __restrict__ dst,
                                                   int E, int* __restrict__ cnt) {
  int e = blockIdx.x * 256 + threadIdx.x;
  if (e < E) atomicAdd(cnt + dst[e], 1);
}

__global__ __launch_bounds__(256) void scan1(const int* __restrict__ cnt, int n,
                                             int* __restrict__ bsums) {
  int base = blockIdx.x * 1024;
  int s = 0;
  for (int i = threadIdx.x; i < 1024; i += 256) {
    int idx = base + i;
    s += (idx < n) ? cnt[idx] : 0;
  }
  __shared__ int red[256];
  red[threadIdx.x] = s;
  __syncthreads();
  for (int off = 128; off > 0; off >>= 1) {
    if (threadIdx.x < off) red[threadIdx.x] += red[threadIdx.x + off];
    __syncthreads();
  }
  if (threadIdx.x == 0) bsums[blockIdx.x] = red[0];
}

__global__ __launch_bounds__(256) void scan2(int* __restrict__ bsums, int nb) {
  // single block, nb <= 256
  int t = threadIdx.x;
  __shared__ int buf[256];
  int v = (t < nb) ? bsums[t] : 0;
  buf[t] = v;
  __syncthreads();
  for (int off = 1; off < 256; off <<= 1) {
    int tv = (t >= off) ? buf[t - off] : 0;
    __syncthreads();
    buf[t] += tv;
    __syncthreads();
  }
  if (t < nb) bsums[t] = buf[t] - v;  // exclusive
}

__global__ __launch_bounds__(256) void scan3(const int* __restrict__ cnt, int n,
                                             const int* __restrict__ bsums,
                                             int* __restrict__ rowptr) {
  int base = blockIdx.x * 1024;
  int t = threadIdx.x;
  int v[4], s = 0;
#pragma unroll
  for (int j = 0; j < 4; j++) {
    int idx = base + t * 4 + j;
    v[j] = (idx < n) ? cnt[idx] : 0;
    s += v[j];
  }
  __shared__ int buf[256];
  buf[t] = s;
  __syncthreads();
  for (int off = 1; off < 256; off <<= 1) {
    int tv = (t >= off) ? buf[t - off] : 0;
    __syncthreads();
    buf[t] += tv;
    __syncthreads();
  }
  int excl = buf[t] - s + bsums[blockIdx.x];
#pragma unroll
  for (int j = 0; j < 4; j++) {
    int idx = base + t * 4 + j;
    if (idx < n) rowptr[idx] = excl;
    excl += v[j];
  }
}

__global__ __launch_bounds__(256) void fill_kernel(const int* __restrict__ src,
                                                   const int* __restrict__ dst,
                                                   int E, int* __restrict__ rowptr,
                                                   int* __restrict__ csrc) {
  int e = blockIdx.x * 256 + threadIdx.x;
  if (e >= E) return;
  int pos = atomicAdd(rowptr + dst[e], 1);  // rowptr becomes segment ENDs
  csrc[pos] = src[e];
}

// ---------------------------------------------------------------------------
// gather_attn: 8-lane group per dst node; online softmax over incoming edges.
// kvt: [N_src][64] = k_rel | v_rel interleaved. rowptr holds segment ENDs
// (start of d = rowptr[d-1], or 0 for d==0). outs row += softmax-weighted sum.
// ---------------------------------------------------------------------------
__device__ __forceinline__ void osm_upd(float& m, float& l, float4& a, float sc,
                                        float4 v4) {
  float mn = fmaxf(m, sc);
  float s = __expf(m - mn);
  float ex = __expf(sc - mn);
  l = l * s + ex;
  a.x = a.x * s + ex * v4.x;
  a.y = a.y * s + ex * v4.y;
  a.z = a.z * s + ex * v4.z;
  a.w = a.w * s + ex * v4.w;
  m = mn;
}

__global__ __launch_bounds__(256) void gather_attn(
    const int* __restrict__ rowptr, const int* __restrict__ csrc, int n_dst,
    const float* __restrict__ qT, const float* __restrict__ kvt,
    float* __restrict__ outs) {
  int t = blockIdx.x * 256 + threadIdx.x;
  int d = t >> 3, g = t & 7;
  if (d >= n_dst) return;
  int beg = d ? rowptr[d - 1] : 0;
  int end = rowptr[d];
  if (beg == end) return;
  float4 q4 = *reinterpret_cast<const float4*>(qT + (long)d * 32 + g * 4);
  // two independent online-softmax states for MLP (merged below)
  float m0 = -3.4e38f, l0 = 0.f, m1 = -3.4e38f, l1 = 0.f;
  float4 a0 = make_float4(0, 0, 0, 0), a1 = make_float4(0, 0, 0, 0);
  int e = beg;
  for (; e + 1 < end; e += 2) {
    int s0 = csrc[e], s1 = csrc[e + 1];
    const float* p0 = kvt + (long)s0 * 64;
    const float* p1 = kvt + (long)s1 * 64;
    float4 k0 = *reinterpret_cast<const float4*>(p0 + g * 4);
    float4 k1 = *reinterpret_cast<const float4*>(p1 + g * 4);
    float4 v0 = *reinterpret_cast<const float4*>(p0 + 32 + g * 4);
    float4 v1 = *reinterpret_cast<const float4*>(p1 + 32 + g * 4);
    float sc0 = q4.x * k0.x + q4.y * k0.y + q4.z * k0.z + q4.w * k0.w;
    float sc1 = q4.x * k1.x + q4.y * k1.y + q4.z * k1.z + q4.w * k1.w;
    sc0 += __shfl_xor(sc0, 1); sc1 += __shfl_xor(sc1, 1);
    sc0 += __shfl_xor(sc0, 2); sc1 += __shfl_xor(sc1, 2);
    sc0 += __shfl_xor(sc0, 4); sc1 += __shfl_xor(sc1, 4);
    osm_upd(m0, l0, a0, sc0, v0);
    osm_upd(m1, l1, a1, sc1, v1);
  }
  if (e < end) {
    int s0 = csrc[e];
    const float* p0 = kvt + (long)s0 * 64;
    float4 k0 = *reinterpret_cast<const float4*>(p0 + g * 4);
    float4 v0 = *reinterpret_cast<const float4*>(p0 + 32 + g * 4);
    float sc0 = q4.x * k0.x + q4.y * k0.y + q4.z * k0.z + q4.w * k0.w;
    sc0 += __shfl_xor(sc0, 1);
    sc0 += __shfl_xor(sc0, 2);
    sc0 += __shfl_xor(sc0, 4);
    osm_upd(m0, l0, a0, sc0, v0);
  }
  // merge states (empty state has m=-3.4e38 -> weight 0)
  float mn = fmaxf(m0, m1);
  float w0 = __expf(m0 - mn), w1 = __expf(m1 - mn);
  float l = l0 * w0 + l1 * w1;
  float inv = 1.f / l;
  float* o = outs + (long)d * 32 + g * 4;
  float4 prev = *reinterpret_cast<const float4*>(o);
  prev.x += (a0.x * w0 + a1.x * w1) * inv;
  prev.y += (a0.y * w0 + a1.y * w1) * inv;
  prev.z += (a0.z * w0 + a1.z * w1) * inv;
  prev.w += (a0.w * w0 + a1.w * w1) * inv;
  *reinterpret_cast<float4*>(o) = prev;
}

// ---------------------------------------------------------------------------
// Pointwise epilogues.
// ---------------------------------------------------------------------------
__global__ __launch_bounds__(256) void gelu_kernel(
    const float* __restrict__ in, float* __restrict__ out, int n) {
  int i = blockIdx.x * 256 + threadIdx.x;
  if (i >= n) return;
  float x = in[i];
  out[i] = 0.5f * x * (1.f + erff(x * 0.70710678118654752f));
}

__global__ __launch_bounds__(256) void blend_kernel(
    const float* __restrict__ o, const float* __restrict__ xin,
    const void* __restrict__ skipg, void* __restrict__ out, int nAf, int total,
    const int* __restrict__ flag) {
  int i = blockIdx.x * 256 + threadIdx.x;
  if (i >= total) return;
  const int isbf = *flag;
  float g = ldf(skipg, (i < nAf) ? 0 : 1, isbf);
  float a = 1.f / (1.f + __expf(-g));
  float v = a * o[i] + (1.f - a) * xin[i];
  if (isbf) ((bf16*)out)[i] = __float2bfloat16(v);
  else      ((float*)out)[i] = v;
}

// ---------------------------------------------------------------------------
// Host-side: one HGT layer using prebuilt CSR.
// ---------------------------------------------------------------------------
template <int IND, bool EXT>
static void run_layer(const void* xa, const void* xp, const int* flag,
                      const float* w, int* const* rowptr, int* const* csrc,
                      float* q, float* outs, float* kv, float* eout,
                      int NA, int NP, hipStream_t stream) {
  const long NAf = (long)NA * 32;
  const long NPf = (long)NP * 32;
  const int per_qkv = 32 * (IND + 4);
  const int per_a = 32 * 36;
  const float* qW[2] = {w, w + per_qkv};
  const float* kW[3] = {w + 2 * per_qkv, w + 3 * per_qkv, w + 4 * per_qkv};
  const float* vW[3] = {w + 5 * per_qkv, w + 6 * per_qkv, w + 7 * per_qkv};
  const float* aW[2] = {w + 8 * per_qkv, w + 8 * per_qkv + per_a};

  auto LIN = [&](const void* X, const float* W, float* Y, int N, int ldY,
                 int offY) {
    if constexpr (EXT)
      linear_ext<IND><<<(N + 31) / 32, 256, 0, stream>>>(X, W, Y, N, ldY, offY,
                                                         flag);
    else
      linear_f32<IND><<<(N + 31) / 32, 256, 0, stream>>>((const float*)X, W, Y,
                                                         N, ldY, offY);
  };

  // q for both node types
  LIN(xa, qW[0], q, NA, 32, 0);
  LIN(xp, qW[1], q + NAf, NP, 32, 0);
  hipMemsetAsync(outs, 0, (size_t)(NAf + NPf) * 4, stream);

  const void* xs_[3] = {xa, xp, xp};
  const int ns_[3] = {NA, NP, NP};
  const int nd_[3] = {NP, NA, NP};
  float* qdst_[3] = {q + NAf, q, q + NAf};
  float* odst_[3] = {outs + NAf, outs, outs + NAf};

  for (int r = 0; r < 3; r++) {
    // k_rel, v_rel interleaved into kv[N_src][64]
    LIN(xs_[r], kW[r], kv, ns_[r], 64, 0);
    LIN(xs_[r], vW[r], kv, ns_[r], 64, 32);
    gather_attn<<<((long)nd_[r] * 8 + 255) / 256, 256, 0, stream>>>(
        rowptr[r], csrc[r], nd_[r], qdst_[r], kv, odst_[r]);
  }

  // epilogue: gelu(outs) -> q (free now), then @Wa + ba -> eout
  int tot = (int)(NAf + NPf);
  gelu_kernel<<<(tot + 255) / 256, 256, 0, stream>>>(outs, q, tot);
  linear_f32<32><<<(NA + 31) / 32, 256, 0, stream>>>(q, aW[0], eout, NA, 32, 0);
  linear_f32<32><<<(NP + 31) / 32, 256, 0, stream>>>(q + NAf, aW[1], eout + NAf,
                                                     NP, 32, 0);
}

extern "C" void kernel_launch(void* const* d_in, const int* in_sizes, int n_in,
                              void* d_out, int out_size, void* d_ws,
                              size_t ws_size, hipStream_t stream) {
  const void* x_a = d_in[0];
  const void* x_p = d_in[1];
  const int* ed[3] = {(const int*)d_in[2], (const int*)d_in[3],
                      (const int*)d_in[4]};
  const int NA = in_sizes[0] / 128;
  const int NP = in_sizes[1] / 128;
  const int E[3] = {in_sizes[2] / 2, in_sizes[3] / 2, in_sizes[4] / 2};
  const int ND[3] = {NP, NA, NP};
  const int NMAX = (NP > NA) ? NP : NA;

  // ---- workspace layout (f32/i32 units) ----
  const size_t W1SZ = 8 * 32 * 132 + 2 * 32 * 36;  // 36096
  const size_t W2SZ = 10 * 32 * 36;                // 11520
  const size_t NT32 = (size_t)(NA + NP) * 32;
  int* flag = (int*)d_ws;
  float* w1 = (float*)d_ws + 16;
  float* w2 = w1 + W1SZ;
  float* q = w2 + W2SZ;
  float* outs = q + NT32;
  float* x2 = outs + NT32;
  float* kv = x2 + NT32;                    // NMAX*64
  int* rp0 = (int*)(kv + (size_t)NMAX * 64);
  int* rp1 = rp0 + ND[0];
  int* rp2 = rp1 + ND[1];
  int* cs0 = rp2 + ND[2];
  int* cs1 = cs0 + E[0];
  int* cs2 = cs1 + E[1];
  int* cnt = cs2 + E[2];                    // NMAX
  int* bsums = cnt + NMAX;                  // 256
  int* rowptr[3] = {rp0, rp1, rp2};
  int* csrc[3] = {cs0, cs1, cs2};
  (void)ws_size; (void)n_in;

  // ---- dtype sniff (bf16 vs f32) on x_author ----
  detect_dtype<<<1, 256, 0, stream>>>((const unsigned*)x_a, 4096, flag);

  // ---- combined weights ----
  {
    int tot1 = 8 * 32 * 132 + 2 * 32 * 36;
    prep_weights<<<(tot1 + 255) / 256, 256, 0, stream>>>(
        d_in[5], d_in[6], d_in[7], d_in[8], d_in[9], d_in[10], d_in[11],
        d_in[12], d_in[14], d_in[15], d_in[16], w1, 128, flag);
    int tot2 = 10 * 32 * 36;
    prep_weights<<<(tot2 + 255) / 256, 256, 0, stream>>>(
        d_in[17], d_in[18], d_in[19], d_in[20], d_in[21], d_in[22], d_in[23],
        d_in[24], d_in[26], d_in[27], d_in[28], w2, 32, flag);
  }

  // ---- CSR build (once; reused by both layers) ----
  for (int r = 0; r < 3; r++) {
    const int n = ND[r];
    const int* srcp = ed[r];
    const int* dstp = ed[r] + E[r];
    const int nb = (n + 1023) / 1024;  // <= 196 for n <= 200000
    hipMemsetAsync(cnt, 0, (size_t)n * 4, stream);
    hist_kernel<<<(E[r] + 255) / 256, 256, 0, stream>>>(dstp, E[r], cnt);
    scan1<<<nb, 256, 0, stream>>>(cnt, n, bsums);
    scan2<<<1, 256, 0, stream>>>(bsums, nb);
    scan3<<<nb, 256, 0, stream>>>(cnt, n, bsums, rowptr[r]);
    fill_kernel<<<(E[r] + 255) / 256, 256, 0, stream>>>(srcp, dstp, E[r],
                                                        rowptr[r], csrc[r]);
  }

  // ---- layer 1: x [128] -> x2 (f32), no skip ----
  run_layer<128, true>(x_a, x_p, flag, w1, rowptr, csrc, q, outs, kv, x2, NA,
                       NP, stream);

  // ---- layer 2: f32 x2 [32] -> outs (f32), then gated skip -> d_out ----
  run_layer<32, false>(x2, x2 + (size_t)NA * 32, flag, w2, rowptr, csrc, q,
                       outs, kv, outs, NA, NP, stream);
  blend_kernel<<<(out_size + 255) / 256, 256, 0, stream>>>(
      outs, x2, d_in[25], d_out, NA * 32, out_size, flag);
}

// Round 8
// 1776.877 us; speedup vs baseline: 3.1868x; 1.3017x over previous
//
#include <hip/hip_runtime.h>
#include <hip/hip_bf16.h>

typedef __hip_bfloat16 bf16;

__device__ __forceinline__ float u2f(unsigned short u) {
  return __uint_as_float(((unsigned)u) << 16);
}
__device__ __forceinline__ float b2f(bf16 v) { return __bfloat162float(v); }

// generic scalar load: isbf selects bf16 vs f32 interpretation of p
__device__ __forceinline__ float ldf(const void* p, long i, int isbf) {
  if (isbf) return b2f(((const bf16*)p)[i]);
  return ((const float*)p)[i];
}

__device__ __forceinline__ float4 loadx4(const bf16* X, long off) {
  const unsigned short* p = reinterpret_cast<const unsigned short*>(X) + off;
  ushort4 u = *reinterpret_cast<const ushort4*>(p);
  return make_float4(u2f(u.x), u2f(u.y), u2f(u.z), u2f(u.w));
}
__device__ __forceinline__ float4 loadx4(const float* X, long off) {
  return *reinterpret_cast<const float4*>(X + off);
}

__device__ __forceinline__ float gelu1(float x) {
  return 0.5f * x * (1.f + erff(x * 0.70710678118654752f));
}

// ---------------------------------------------------------------------------
// detect_dtype: decide if float inputs are bf16 (flag=1) or f32 (flag=0).
// ---------------------------------------------------------------------------
__global__ __launch_bounds__(256) void detect_dtype(
    const unsigned* __restrict__ x, int nwords, int* __restrict__ flag) {
  __shared__ int cnt;
  if (threadIdx.x == 0) cnt = 0;
  __syncthreads();
  int c = 0;
  for (int i = threadIdx.x; i < nwords; i += 256) {
    unsigned h = x[i] & 0xFFFFu;
    unsigned e = (h >> 7) & 0xFFu;
    if ((e >= 0x70u && e <= 0x85u) || (h & 0x7FFFu) == 0u) c++;
  }
  atomicAdd(&cnt, c);
  __syncthreads();
  if (threadIdx.x == 0) *flag = (2 * cnt > nwords) ? 1 : 0;
}

// ---------------------------------------------------------------------------
// prep_weights: transposed f32 combined weights, job order
// {q0, k_r0, v_r0, q1, k_r1, v_r1, k_r2, v_r2, a0, a1} so that the fused
// projection launches read contiguous weight blocks:
//   authors: jobs 0-2 | papersA: jobs 3-5 | papersB: jobs 6-7 | a: 8-9.
// qkv jobs: WT[32][inD+4] ([c][inD]=bias); a jobs: WT[32][36].
// k jobs fold arel[r] and prel[r]/sqrt(32); v jobs fold mrel[r].
// ---------------------------------------------------------------------------
__global__ __launch_bounds__(256) void prep_weights(
    const void* __restrict__ Wk, const void* __restrict__ bk,
    const void* __restrict__ Wq, const void* __restrict__ bq,
    const void* __restrict__ Wv, const void* __restrict__ bv,
    const void* __restrict__ Wa, const void* __restrict__ ba,
    const void* __restrict__ arel, const void* __restrict__ mrel,
    const void* __restrict__ prel, float* __restrict__ out, int inD,
    const int* __restrict__ flag) {
  const int isbf = *flag;
  const int per_qkv = 32 * (inD + 4);
  const int per_a = 32 * 36;
  const int total = 8 * per_qkv + 2 * per_a;
  int tid = blockIdx.x * 256 + threadIdx.x;
  if (tid >= total) return;
  int job, rem, S, IND;
  if (tid < 8 * per_qkv) {
    job = tid / per_qkv; rem = tid % per_qkv; S = inD + 4; IND = inD;
  } else {
    int t2 = tid - 8 * per_qkv;
    job = 8 + t2 / per_a; rem = t2 % per_a; S = 36; IND = 32;
  }
  int c = rem / S, i = rem % S;
  float val = 0.f;
  if (job == 0 || job == 3) {  // q: plain transpose of Wq[t], bias row
    int t = (job == 3);
    if (i < IND)       val = ldf(Wq, ((long)t * IND + i) * 32 + c, isbf);
    else if (i == IND) val = ldf(bq, t * 32 + c, isbf);
  } else if (job < 8) {  // k/v: fold relation matrix
    int r = (job <= 2) ? 0 : (job <= 5 ? 1 : 2);
    bool isk = (job == 1 || job == 4 || job == 6);
    int s = (r == 0) ? 0 : 1;  // EDGE_META src types {0,1,1}
    const void* W = isk ? Wk : Wv;
    const void* bb = isk ? bk : bv;
    const void* R = isk ? arel : mrel;
    const long Roff = (long)r * 1024;
    if (i <= IND) {
      float acc = 0.f;
      for (int j = 0; j < 32; j++) {
        float a = (i < IND) ? ldf(W, ((long)s * IND + i) * 32 + j, isbf)
                            : ldf(bb, s * 32 + j, isbf);
        acc += a * ldf(R, Roff + j * 32 + c, isbf);
      }
      if (isk) acc *= ldf(prel, r, isbf) * 0.17677669529663687f;  // prel/sqrt(32)
      val = acc;
    }
  } else {  // a: transpose of Wa[t], bias row
    int t = job - 8;
    if (i < 32)       val = ldf(Wa, ((long)t * 32 + i) * 32 + c, isbf);
    else if (i == 32) val = ldf(ba, t * 32 + c, isbf);
  }
  out[tid] = val;
}

// ---------------------------------------------------------------------------
// flin: fused multi-output linear. Reads X[N][IND] ONCE, computes NMAT
// projections (weights contiguous in WTg, each WT[32][IND+4] with bias).
// Block 256 = 8 rowgroups x 32 cols; 4 rows/thread.
// Output m: P[m][(row)*LD[m] + OF[m] + col].
// ---------------------------------------------------------------------------
template <typename XT, int IND, int NMAT>
__device__ __forceinline__ void flin_body(
    const XT* __restrict__ X, const float* __restrict__ wt,
    float* const* Ps, const int* LDs, const int* OFs, int row0, int col,
    int N) {
  constexpr int S = IND + 4;
  float acc[NMAT][4];
#pragma unroll
  for (int m2 = 0; m2 < NMAT; m2++) {
    float b = wt[(m2 * 32 + col) * S + IND];
#pragma unroll
    for (int r = 0; r < 4; r++) acc[m2][r] = b;
  }
  if (row0 + 3 < N) {
#pragma unroll 2
    for (int j = 0; j < IND; j += 4) {
      float4 xv[4];
#pragma unroll
      for (int r = 0; r < 4; r++) xv[r] = loadx4(X, (long)(row0 + r) * IND + j);
#pragma unroll
      for (int m2 = 0; m2 < NMAT; m2++) {
        float4 w4 = *reinterpret_cast<const float4*>(&wt[(m2 * 32 + col) * S + j]);
#pragma unroll
        for (int r = 0; r < 4; r++)
          acc[m2][r] += xv[r].x * w4.x + xv[r].y * w4.y + xv[r].z * w4.z +
                        xv[r].w * w4.w;
      }
    }
#pragma unroll
    for (int m2 = 0; m2 < NMAT; m2++)
#pragma unroll
      for (int r = 0; r < 4; r++)
        Ps[m2][(long)(row0 + r) * LDs[m2] + OFs[m2] + col] = acc[m2][r];
  } else if (row0 < N) {
    for (int j = 0; j < IND; j += 4) {
#pragma unroll
      for (int r = 0; r < 4; r++) {
        if (row0 + r < N) {
          float4 xv = loadx4(X, (long)(row0 + r) * IND + j);
#pragma unroll
          for (int m2 = 0; m2 < NMAT; m2++) {
            float4 w4 =
                *reinterpret_cast<const float4*>(&wt[(m2 * 32 + col) * S + j]);
            acc[m2][r] += xv.x * w4.x + xv.y * w4.y + xv.z * w4.z + xv.w * w4.w;
          }
        }
      }
    }
#pragma unroll
    for (int m2 = 0; m2 < NMAT; m2++)
#pragma unroll
      for (int r = 0; r < 4; r++)
        if (row0 + r < N)
          Ps[m2][(long)(row0 + r) * LDs[m2] + OFs[m2] + col] = acc[m2][r];
  }
}

template <int IND, int NMAT, bool EXT>
__global__ __launch_bounds__(256) void flin(
    const void* __restrict__ X, const float* __restrict__ WTg, float* P0,
    int LD0, int OF0, float* P1, int LD1, int OF1, float* P2, int LD2, int OF2,
    int N, const int* __restrict__ flag) {
  constexpr int S = IND + 4;
  __shared__ float wt[NMAT * 32 * S];
  for (int idx = threadIdx.x; idx < NMAT * 32 * S; idx += 256)
    wt[idx] = WTg[idx];
  __syncthreads();
  const int col = threadIdx.x & 31;
  const int row0 = blockIdx.x * 32 + (threadIdx.x >> 5) * 4;
  float* Ps[3] = {P0, P1, P2};
  int LDs[3] = {LD0, LD1, LD2};
  int OFs[3] = {OF0, OF1, OF2};
  if (EXT && *flag)
    flin_body<bf16, IND, NMAT>((const bf16*)X, wt, Ps, LDs, OFs, row0, col, N);
  else
    flin_body<float, IND, NMAT>((const float*)X, wt, Ps, LDs, OFs, row0, col, N);
}

// ---------------------------------------------------------------------------
// lin_a_blend: layer-2 epilogue. out = sigmoid(skip[t])*(X@Wa+ba)
//              + (1-sigmoid)*xskip, written as bf16/f32 per flag.
// ---------------------------------------------------------------------------
__global__ __launch_bounds__(256) void lin_a_blend(
    const float* __restrict__ X, const float* __restrict__ WTg,
    const float* __restrict__ xskip, const void* __restrict__ skipg, int tIdx,
    void* __restrict__ out, long elemOff, int N, const int* __restrict__ flag) {
  __shared__ float wt[32 * 36];
  for (int idx = threadIdx.x; idx < 32 * 36; idx += 256) wt[idx] = WTg[idx];
  __syncthreads();
  const int isbf = *flag;
  const int col = threadIdx.x & 31;
  const int row0 = blockIdx.x * 32 + (threadIdx.x >> 5) * 4;
  if (row0 >= N) return;
  const float* wc = wt + col * 36;
  float gv = ldf(skipg, tIdx, isbf);
  float aG = 1.f / (1.f + __expf(-gv));
  float acc[4];
  const float bias = wc[32];
#pragma unroll
  for (int r = 0; r < 4; r++) acc[r] = bias;
  for (int j = 0; j < 32; j += 4) {
    float4 w4 = *reinterpret_cast<const float4*>(wc + j);
#pragma unroll
    for (int r = 0; r < 4; r++) {
      if (row0 + r < N) {
        float4 xv = loadx4(X, (long)(row0 + r) * 32 + j);
        acc[r] += xv.x * w4.x + xv.y * w4.y + xv.z * w4.z + xv.w * w4.w;
      }
    }
  }
#pragma unroll
  for (int r = 0; r < 4; r++) {
    if (row0 + r < N) {
      long idx = (long)(row0 + r) * 32 + col;
      float v = aG * acc[r] + (1.f - aG) * xskip[idx];
      if (isbf) ((bf16*)out)[elemOff + idx] = __float2bfloat16(v);
      else      ((float*)out)[elemOff + idx] = v;
    }
  }
}

// ---------------------------------------------------------------------------
// CSR build over ALL relations at once (concatenated count/rowptr arrays).
// ---------------------------------------------------------------------------
__global__ __launch_bounds__(256) void hist_all(
    const int* __restrict__ d0, const int* __restrict__ d1,
    const int* __restrict__ d2, int E0, int E1, int E2, int b1, int b2,
    int* __restrict__ cnt) {
  int t = blockIdx.x * 256 + threadIdx.x;
  if (t < E0) atomicAdd(cnt + d0[t], 1);
  else if (t < E0 + E1) atomicAdd(cnt + b1 + d1[t - E0], 1);
  else if (t < E0 + E1 + E2) atomicAdd(cnt + b2 + d2[t - E0 - E1], 1);
}

__global__ __launch_bounds__(256) void fill_all(
    const int* __restrict__ s0, const int* __restrict__ d0,
    const int* __restrict__ s1, const int* __restrict__ d1,
    const int* __restrict__ s2, const int* __restrict__ d2, int E0, int E1,
    int E2, int b1, int b2, int* __restrict__ RP, int* __restrict__ csrc) {
  int t = blockIdx.x * 256 + threadIdx.x;
  int sv, idx;
  if (t < E0) { sv = s0[t]; idx = d0[t]; }
  else if (t < E0 + E1) { int e = t - E0; sv = s1[e]; idx = b1 + d1[e]; }
  else if (t < E0 + E1 + E2) { int e = t - E0 - E1; sv = s2[e]; idx = b2 + d2[e]; }
  else return;
  int pos = atomicAdd(RP + idx, 1);  // RP becomes segment ENDs after fill
  csrc[pos] = sv;
}

// 3-level exclusive scan, CHUNK=2048/block (supports n <= 524288).
__global__ __launch_bounds__(256) void scan1(const int* __restrict__ cnt, int n,
                                             int* __restrict__ bsums) {
  int base = blockIdx.x * 2048;
  int s = 0;
  for (int k = 0; k < 8; k++) {
    int idx = base + threadIdx.x + k * 256;
    s += (idx < n) ? cnt[idx] : 0;
  }
  __shared__ int red[256];
  red[threadIdx.x] = s;
  __syncthreads();
  for (int off = 128; off > 0; off >>= 1) {
    if (threadIdx.x < off) red[threadIdx.x] += red[threadIdx.x + off];
    __syncthreads();
  }
  if (threadIdx.x == 0) bsums[blockIdx.x] = red[0];
}

__global__ __launch_bounds__(256) void scan2(int* __restrict__ bsums, int nb) {
  int t = threadIdx.x;
  __shared__ int buf[256];
  int v = (t < nb) ? bsums[t] : 0;
  buf[t] = v;
  __syncthreads();
  for (int off = 1; off < 256; off <<= 1) {
    int tv = (t >= off) ? buf[t - off] : 0;
    __syncthreads();
    buf[t] += tv;
    __syncthreads();
  }
  if (t < nb) bsums[t] = buf[t] - v;  // exclusive
}

__global__ __launch_bounds__(256) void scan3(const int* __restrict__ cnt, int n,
                                             const int* __restrict__ bsums,
                                             int* __restrict__ RP) {
  int base = blockIdx.x * 2048;
  int t = threadIdx.x;
  int v[8], s = 0;
#pragma unroll
  for (int j = 0; j < 8; j++) {
    int idx = base + t * 8 + j;
    v[j] = (idx < n) ? cnt[idx] : 0;
    s += v[j];
  }
  __shared__ int buf[256];
  buf[t] = s;
  __syncthreads();
  for (int off = 1; off < 256; off <<= 1) {
    int tv = (t >= off) ? buf[t - off] : 0;
    __syncthreads();
    buf[t] += tv;
    __syncthreads();
  }
  int excl = buf[t] - s + bsums[blockIdx.x];
#pragma unroll
  for (int j = 0; j < 8; j++) {
    int idx = base + t * 8 + j;
    if (idx < n) RP[idx] = excl;
    excl += v[j];
  }
}

// ---------------------------------------------------------------------------
// gather_attn: 8-lane group per dst node. Reads its q row from qo, runs
// per-relation online softmax over NR CSR ranges (4-way unrolled), sums the
// per-relation results, applies gelu, overwrites the q row in place.
// kv tables: [N_src][64] = k|v. RP holds global segment ENDs.
// ---------------------------------------------------------------------------
__device__ __forceinline__ void osm_upd(float& m, float& l, float4& a, float sc,
                                        float4 v4) {
  float mn = fmaxf(m, sc);
  float s = __expf(m - mn);
  float ex = __expf(sc - mn);
  l = l * s + ex;
  a.x = a.x * s + ex * v4.x;
  a.y = a.y * s + ex * v4.y;
  a.z = a.z * s + ex * v4.z;
  a.w = a.w * s + ex * v4.w;
  m = mn;
}

__device__ __forceinline__ void accum_range(
    const int* __restrict__ RP, long idx, const int* __restrict__ csrc,
    const float* __restrict__ kvt, float4 q4, float4& res) {
  int beg = (idx == 0) ? 0 : RP[idx - 1];
  int end = RP[idx];
  if (beg >= end) return;
  float m0 = -3.4e38f, m1 = -3.4e38f, m2 = -3.4e38f, m3 = -3.4e38f;
  float l0 = 0.f, l1 = 0.f, l2 = 0.f, l3 = 0.f;
  float4 a0 = make_float4(0, 0, 0, 0), a1 = a0, a2 = a0, a3 = a0;
  const int g4 = (threadIdx.x & 7) * 4;
  int e = beg;
  for (; e + 3 < end; e += 4) {
    int s0 = csrc[e], s1 = csrc[e + 1], s2 = csrc[e + 2], s3 = csrc[e + 3];
    const float* p0 = kvt + (long)s0 * 64;
    const float* p1 = kvt + (long)s1 * 64;
    const float* p2 = kvt + (long)s2 * 64;
    const float* p3 = kvt + (long)s3 * 64;
    float4 k0 = *reinterpret_cast<const float4*>(p0 + g4);
    float4 k1 = *reinterpret_cast<const float4*>(p1 + g4);
    float4 k2 = *reinterpret_cast<const float4*>(p2 + g4);
    float4 k3 = *reinterpret_cast<const float4*>(p3 + g4);
    float4 v0 = *reinterpret_cast<const float4*>(p0 + 32 + g4);
    float4 v1 = *reinterpret_cast<const float4*>(p1 + 32 + g4);
    float4 v2 = *reinterpret_cast<const float4*>(p2 + 32 + g4);
    float4 v3 = *reinterpret_cast<const float4*>(p3 + 32 + g4);
    float c0 = q4.x * k0.x + q4.y * k0.y + q4.z * k0.z + q4.w * k0.w;
    float c1 = q4.x * k1.x + q4.y * k1.y + q4.z * k1.z + q4.w * k1.w;
    float c2 = q4.x * k2.x + q4.y * k2.y + q4.z * k2.z + q4.w * k2.w;
    float c3 = q4.x * k3.x + q4.y * k3.y + q4.z * k3.z + q4.w * k3.w;
    c0 += __shfl_xor(c0, 1); c1 += __shfl_xor(c1, 1);
    c2 += __shfl_xor(c2, 1); c3 += __shfl_xor(c3, 1);
    c0 += __shfl_xor(c0, 2); c1 += __shfl_xor(c1, 2);
    c2 += __shfl_xor(c2, 2); c3 += __shfl_xor(c3, 2);
    c0 += __shfl_xor(c0, 4); c1 += __shfl_xor(c1, 4);
    c2 += __shfl_xor(c2, 4); c3 += __shfl_xor(c3, 4);
    osm_upd(m0, l0, a0, c0, v0);
    osm_upd(m1, l1, a1, c1, v1);
    osm_upd(m2, l2, a2, c2, v2);
    osm_upd(m3, l3, a3, c3, v3);
  }
  for (; e < end; e++) {
    int s0 = csrc[e];
    const float* p0 = kvt + (long)s0 * 64;
    float4 k0 = *reinterpret_cast<const float4*>(p0 + g4);
    float4 v0 = *reinterpret_cast<const float4*>(p0 + 32 + g4);
    float c0 = q4.x * k0.x + q4.y * k0.y + q4.z * k0.z + q4.w * k0.w;
    c0 += __shfl_xor(c0, 1);
    c0 += __shfl_xor(c0, 2);
    c0 += __shfl_xor(c0, 4);
    osm_upd(m0, l0, a0, c0, v0);
  }
  // merge 4 states (one joint softmax within this relation)
  float mn = fmaxf(fmaxf(m0, m1), fmaxf(m2, m3));
  float w0 = __expf(m0 - mn), w1 = __expf(m1 - mn);
  float w2 = __expf(m2 - mn), w3 = __expf(m3 - mn);
  float lt = l0 * w0 + l1 * w1 + l2 * w2 + l3 * w3;
  float inv = 1.f / lt;  // lt >= 1 (max-score state contributes exp(0))
  res.x += (a0.x * w0 + a1.x * w1 + a2.x * w2 + a3.x * w3) * inv;
  res.y += (a0.y * w0 + a1.y * w1 + a2.y * w2 + a3.y * w3) * inv;
  res.z += (a0.z * w0 + a1.z * w1 + a2.z * w2 + a3.z * w3) * inv;
  res.w += (a0.w * w0 + a1.w * w1 + a2.w * w2 + a3.w * w3) * inv;
}

template <int NR>
__global__ __launch_bounds__(256) void gather_attn(
    const int* __restrict__ RP, const int* __restrict__ csrc, int n_dst,
    long base0, const float* __restrict__ kv0, long base1,
    const float* __restrict__ kv1, float* __restrict__ qo) {
  int t = blockIdx.x * 256 + threadIdx.x;
  int d = t >> 3, g = t & 7;
  if (d >= n_dst) return;
  float* row = qo + (long)d * 32 + g * 4;
  float4 q4 = *reinterpret_cast<const float4*>(row);
  float4 res = make_float4(0, 0, 0, 0);
  accum_range(RP, base0 + d, csrc, kv0, q4, res);
  if (NR == 2) accum_range(RP, base1 + d, csrc, kv1, q4, res);
  res.x = gelu1(res.x);
  res.y = gelu1(res.y);
  res.z = gelu1(res.z);
  res.w = gelu1(res.w);
  *reinterpret_cast<float4*>(row) = res;
}

extern "C" void kernel_launch(void* const* d_in, const int* in_sizes, int n_in,
                              void* d_out, int out_size, void* d_ws,
                              size_t ws_size, hipStream_t stream) {
  const void* x_a = d_in[0];
  const void* x_p = d_in[1];
  const int* ed[3] = {(const int*)d_in[2], (const int*)d_in[3],
                      (const int*)d_in[4]};
  const int NA = in_sizes[0] / 128;
  const int NP = in_sizes[1] / 128;
  const int E0 = in_sizes[2] / 2, E1 = in_sizes[3] / 2, E2 = in_sizes[4] / 2;
  const int TE = E0 + E1 + E2;
  const long NAf = (long)NA * 32;
  // concatenated dst-index space: r0 (papers) | r1 (authors) | r2 (papers)
  const int B1 = NP, B2 = NP + NA;
  const int NSEG = NP + NA + NP;

  // ---- workspace layout ----
  const size_t W1SZ = 8 * 32 * 132 + 2 * 32 * 36;  // 36096
  const size_t W2SZ = 10 * 32 * 36;                // 11520
  int* flag = (int*)d_ws;
  float* w1 = (float*)d_ws + 16;
  float* w2 = w1 + W1SZ;
  float* outs = w2 + W2SZ;                   // (NA+NP)*32: q rows -> attn rows
  float* x2 = outs + (size_t)(NA + NP) * 32; // layer-1 output (skip input)
  float* kvA = x2 + (size_t)(NA + NP) * 32;  // NA*64 (k0|v0)
  float* kvP = kvA + (size_t)NA * 64;        // NP*64 (k1|v1 then k2|v2)
  int* RP = (int*)(kvP + (size_t)NP * 64);   // NSEG
  int* csrc = RP + NSEG;                     // TE
  int* cnt = csrc + TE;                      // NSEG
  int* bsums = cnt + NSEG;                   // 256
  int* rowptr[3];
  rowptr[0] = RP;  // silence unused warnings pattern kept minimal
  (void)rowptr; (void)ws_size; (void)n_in;

  // ---- dtype sniff ----
  detect_dtype<<<1, 256, 0, stream>>>((const unsigned*)x_a, 4096, flag);

  // ---- combined weights ----
  {
    int tot1 = (int)W1SZ;
    prep_weights<<<(tot1 + 255) / 256, 256, 0, stream>>>(
        d_in[5], d_in[6], d_in[7], d_in[8], d_in[9], d_in[10], d_in[11],
        d_in[12], d_in[14], d_in[15], d_in[16], w1, 128, flag);
    int tot2 = (int)W2SZ;
    prep_weights<<<(tot2 + 255) / 256, 256, 0, stream>>>(
        d_in[17], d_in[18], d_in[19], d_in[20], d_in[21], d_in[22], d_in[23],
        d_in[24], d_in[26], d_in[27], d_in[28], w2, 32, flag);
  }

  // ---- unified CSR build (reused by both layers) ----
  hipMemsetAsync(cnt, 0, (size_t)NSEG * 4, stream);
  hist_all<<<(TE + 255) / 256, 256, 0, stream>>>(
      ed[0] + E0, ed[1] + E1, ed[2] + E2, E0, E1, E2, B1, B2, cnt);
  {
    int nb = (NSEG + 2047) / 2048;  // <= 256 for NSEG <= 524288
    scan1<<<nb, 256, 0, stream>>>(cnt, NSEG, bsums);
    scan2<<<1, 256, 0, stream>>>(bsums, nb);
    scan3<<<nb, 256, 0, stream>>>(cnt, NSEG, bsums, RP);
  }
  fill_all<<<(TE + 255) / 256, 256, 0, stream>>>(
      ed[0], ed[0] + E0, ed[1], ed[1] + E1, ed[2], ed[2] + E2, E0, E1, E2, B1,
      B2, RP, csrc);

  // ---- two HGT layers ----
  for (int layer = 0; layer < 2; layer++) {
    const float* w = layer ? w2 : w1;
    const int PQ = layer ? 32 * 36 : 32 * 132;
    const void* xa = layer ? (const void*)x2 : x_a;
    const void* xp = layer ? (const void*)(x2 + NAf) : x_p;
    const int gA = (NA + 31) / 32, gP = (NP + 31) / 32;

    // projections (q into outs rows; k|v interleaved into kv tables)
    auto launch_flin3 = [&](const void* X, const float* W, float* q0,
                            float* kvt, int N, int grid) {
      if (layer == 0)
        flin<128, 3, true><<<grid, 256, 0, stream>>>(
            X, W, q0, 32, 0, kvt, 64, 0, kvt, 64, 32, N, flag);
      else
        flin<32, 3, false><<<grid, 256, 0, stream>>>(
            X, W, q0, 32, 0, kvt, 64, 0, kvt, 64, 32, N, flag);
    };
    launch_flin3(xa, w + 0 * PQ, outs, kvA, NA, gA);         // q_a,k0,v0
    launch_flin3(xp, w + 3 * PQ, outs + NAf, kvP, NP, gP);   // q_p,k1,v1

    // authors receive r1 (src=papers, kvP=k1|v1); in-place q->gelu(attn)
    gather_attn<1><<<((long)NA * 8 + 255) / 256, 256, 0, stream>>>(
        RP, csrc, NA, B1, kvP, 0, nullptr, outs);

    // overwrite kvP with k2|v2, then papers receive r0 (kvA) + r2 (kvP)
    if (layer == 0)
      flin<128, 2, true><<<gP, 256, 0, stream>>>(
          xp, w + 6 * PQ, kvP, 64, 0, kvP, 64, 32, nullptr, 0, 0, NP, flag);
    else
      flin<32, 2, false><<<gP, 256, 0, stream>>>(
          xp, w + 6 * PQ, kvP, 64, 0, kvP, 64, 32, nullptr, 0, 0, NP, flag);
    gather_attn<2><<<((long)NP * 8 + 255) / 256, 256, 0, stream>>>(
        RP, csrc, NP, 0, kvA, B2, kvP, outs + NAf);

    // epilogue
    if (layer == 0) {
      // x2 = gelu'd-attn @ Wa1 + ba1 (no skip)
      flin<32, 1, false><<<gA, 256, 0, stream>>>(
          outs, w + 8 * PQ, x2, 32, 0, nullptr, 0, 0, nullptr, 0, 0, NA, flag);
      flin<32, 1, false><<<gP, 256, 0, stream>>>(
          outs + NAf, w + 8 * PQ + 32 * 36, x2 + NAf, 32, 0, nullptr, 0, 0,
          nullptr, 0, 0, NP, flag);
    } else {
      // d_out = sigmoid(skip2)*(... @ Wa2 + ba2) + (1-sigmoid)*x2
      lin_a_blend<<<gA, 256, 0, stream>>>(outs, w + 8 * PQ, x2, d_in[25], 0,
                                          d_out, 0, NA, flag);
      lin_a_blend<<<gP, 256, 0, stream>>>(outs + NAf, w + 8 * PQ + 32 * 36,
                                          x2 + NAf, d_in[25], 1, d_out, NAf,
                                          NP, flag);
    }
  }
}